// Round 1
// baseline (399.040 us; speedup 1.0000x reference)
//
#include <hip/hip_runtime.h>
#include <hip/hip_bf16.h>

using u16 = unsigned short;
using u32 = unsigned int;

typedef __attribute__((ext_vector_type(8))) short bf16x8;
typedef __attribute__((ext_vector_type(4))) float f32x4;
typedef __attribute__((ext_vector_type(2))) float f32x2;
typedef __attribute__((ext_vector_type(4))) u32 u32x4;

#define MFMA16(a, b, c) __builtin_amdgcn_mfma_f32_16x16x32_bf16((a), (b), (c), 0, 0, 0)

union FragU { u32 u[4]; bf16x8 v; u32x4 q; };

__device__ __forceinline__ bf16x8 mk_frag(u32 a, u32 b, u32 c, u32 d) {
  FragU f; f.u[0] = a; f.u[1] = b; f.u[2] = c; f.u[3] = d; return f.v;
}
__device__ __forceinline__ bf16x8 as_frag(u32x4 x) { FragU f; f.q = x; return f.v; }

__device__ __forceinline__ u16 f2bf(float x) {
  __hip_bfloat16 h = __float2bfloat16(x);
  u16 r; __builtin_memcpy(&r, &h, 2); return r;
}

__device__ __forceinline__ u32 pk_bf16(float a, float b) {
  __hip_bfloat162 h = __float22bfloat162_rn(make_float2(a, b));
  u32 r; __builtin_memcpy(&r, &h, 4); return r;
}

__device__ __forceinline__ float fast_tanh(float x) {
  // tanh(x) = 1 - 2/(1 + exp2(x * 2*log2(e)))
  float t = __builtin_amdgcn_exp2f(x * 2.885390081777927f);
  return __builtin_fmaf(-2.0f, __builtin_amdgcn_rcpf(1.0f + t), 1.0f);
}

// Flipped orientation: every layer computes D[hidden][point] with A = W^T, B = activations.
// With contraction order K(ks,8q+j) = 32ks + 16*(j>>2) + 4q + (j&3), the next layer's
// B-fragment is exactly the lane's OWN packed tanh outputs of D-tiles 2ks, 2ks+1:
//   Bfrag(ks) = { P[2ks][0], P[2ks][1], P[2ks+1][0], P[2ks+1][1] },
//   P[t][w] = pk_bf16(tanh(acc_t[2w]), tanh(acc_t[2w+1]))   (rows 16t+4q+{0..3}, col = point c)
// => activations stay in registers; no LDS hbuf, no shuffles, no repacks.
//
// Weight A-frag LDS layout (W2T/W3T): row n = hid_out (256 B), chunk kc = 4ks+q stored at
// position kc ^ (n&15) (proven conflict-free pattern), chunk bytes hold the 8 bf16 at
// hid_in = K(ks, 8q+j), j = 0..7. Biases ride in as the MFMA C-operand (layers 2/3) or as
// an augmented K=5 input slot (layer 1: inputs (x,y,c1,c2,1), W1 row 4 = b1).

#define LDS_W2 0          // 32768 B
#define LDS_W3 32768      // 32768 B
#define LDS_W4 65536      //   512 B (2 rows x 256)
#define LDS_B2 66048      //   512 B f32[128]
#define LDS_B3 66560      //   512 B f32[128]
#define LDS_W1 67072      //  2048 B (128 rows x 16 B, q==0 A-chunk incl. bias at j=4)
#define LDS_TOTAL 69120   // 2 WGs/CU co-resident (138240 <= 163840)

#define LAYER_FC(PSU, PSV, PDU, PDV, WOFF, BOFF)                                              \
  {                                                                                           \
    _Pragma("unroll")                                                                         \
    for (int t = 0; t < 8; t++) {                                                             \
      f32x4 bi = *(const f32x4*)(lds + (BOFF) + t * 64 + biasaddr);                           \
      f32x4 acu = bi, acv = bi;                                                               \
      _Pragma("unroll")                                                                       \
      for (int ks = 0; ks < 4; ks++) {                                                        \
        bf16x8 aw = *(const bf16x8*)(lds + (WOFF) + t * 4096 + posA[ks]);                     \
        acu = MFMA16(aw, mk_frag(PSU[4*ks], PSU[4*ks+1], PSU[4*ks+2], PSU[4*ks+3]), acu);     \
        acv = MFMA16(aw, mk_frag(PSV[4*ks], PSV[4*ks+1], PSV[4*ks+2], PSV[4*ks+3]), acv);     \
      }                                                                                       \
      PDU[2*t]   = pk_bf16(fast_tanh(acu[0]), fast_tanh(acu[1]));                             \
      PDU[2*t+1] = pk_bf16(fast_tanh(acu[2]), fast_tanh(acu[3]));                             \
      PDV[2*t]   = pk_bf16(fast_tanh(acv[0]), fast_tanh(acv[1]));                             \
      PDV[2*t+1] = pk_bf16(fast_tanh(acv[2]), fast_tanh(acv[3]));                             \
    }                                                                                         \
  }

__global__ void __launch_bounds__(512, 4) mlp_fused(
    const float* __restrict__ Xg, const float* __restrict__ Yg,
    const float* __restrict__ C1g, const float* __restrict__ C2g,
    const float* __restrict__ W1g, const float* __restrict__ B1g,
    const float* __restrict__ W2g, const float* __restrict__ B2g,
    const float* __restrict__ W3g, const float* __restrict__ B3g,
    const float* __restrict__ W4g, const float* __restrict__ B4g,
    float* __restrict__ Og, int npts, int nwaves_total)
{
  extern __shared__ char lds[];
  const int tid = threadIdx.x;

  // ---- stage W2^T / W3^T as K-interleaved, bank-swizzled A-fragments ----
  for (int i = tid; i < 16384; i += 512) {
    int k = i >> 7, n = i & 127;                       // W[k][n], k = hid_in, n = hid_out
    int kc = ((k >> 5) << 2) | ((k >> 2) & 3);         // chunk = 4*ks + q
    int j  = (k & 3) | (((k >> 4) & 1) << 2);          // slot within chunk
    int off = n * 256 + ((kc ^ (n & 15)) << 4) + (j << 1);
    *(u16*)(lds + LDS_W2 + off) = f2bf(W2g[i]);
    *(u16*)(lds + LDS_W3 + off) = f2bf(W3g[i]);
  }
  if (tid < 256) {                                     // W4 is [128][2] row-major
    int k = tid >> 1, o = tid & 1;
    int kc = ((k >> 5) << 2) | ((k >> 2) & 3);
    int j  = (k & 3) | (((k >> 4) & 1) << 2);
    *(u16*)(lds + LDS_W4 + o * 256 + (kc << 4) + (j << 1)) = f2bf(W4g[tid]);
  }
  if (tid < 128) {
    ((float*)(lds + LDS_B2))[tid] = B2g[tid];
    ((float*)(lds + LDS_B3))[tid] = B3g[tid];
    // W1 augmented A-chunk (q==0 only): j=0..3 -> W1[0..3][n], j=4 -> b1[n]
    u32* w1r = (u32*)(lds + LDS_W1 + tid * 16);
    w1r[0] = pk_bf16(W1g[tid],       W1g[128 + tid]);
    w1r[1] = pk_bf16(W1g[256 + tid], W1g[384 + tid]);
    w1r[2] = pk_bf16(B1g[tid], 0.f);
    w1r[3] = 0u;
  }
  __syncthreads();

  const int wave = tid >> 6;
  const int lane = tid & 63;
  const int q = lane >> 4;
  const int c = lane & 15;
  const int wgid = blockIdx.x * 8 + wave;

  int posA[4];
#pragma unroll
  for (int ks = 0; ks < 4; ks++) posA[ks] = c * 256 + (((ks * 4 + q) ^ c) << 4);
  const int biasaddr = q * 16;
  const int w4addr = (c & 1) * 256 + q * 16;   // c>=2 lanes duplicate rows -> unused D rows
  const float b4_0 = B4g[0], b4_1 = B4g[1];

  const int nbatch = npts >> 5;   // 32 points (2 tiles of 16) per wave-iteration

  // software-pipelined input fetch: q==0 lanes hold layer-1 B-frag words (k=4 slot = 1.0)
  u32 b1u0 = 0, b1u1 = 0, b1u2 = 0, b1v0 = 0, b1v1 = 0, b1v2 = 0;
  if (wgid < nbatch && q == 0) {
    int iu = (wgid << 5) + c, iv = iu + 16;
    b1u0 = pk_bf16(Xg[iu], Yg[iu]); b1u1 = pk_bf16(C1g[iu], C2g[iu]); b1u2 = 0x00003f80u;
    b1v0 = pk_bf16(Xg[iv], Yg[iv]); b1v1 = pk_bf16(C1g[iv], C2g[iv]); b1v2 = 0x00003f80u;
  }

  for (int b = wgid; b < nbatch; b += nwaves_total) {
    const int pb = b << 5;

    // ---- layer 1 (K=5 augmented; bias folded into A row 4) ----
    u32 pu[16], pv[16];
#pragma unroll
    for (int t = 0; t < 8; t++) {
      u32x4 wf = {0u, 0u, 0u, 0u};
      if (q == 0) wf = *(const u32x4*)(lds + LDS_W1 + t * 256 + c * 16);
      f32x4 z = {0.f, 0.f, 0.f, 0.f};
      f32x4 acu = MFMA16(as_frag(wf), mk_frag(b1u0, b1u1, b1u2, 0u), z);
      f32x4 acv = MFMA16(as_frag(wf), mk_frag(b1v0, b1v1, b1v2, 0u), z);
      pu[2*t]   = pk_bf16(fast_tanh(acu[0]), fast_tanh(acu[1]));
      pu[2*t+1] = pk_bf16(fast_tanh(acu[2]), fast_tanh(acu[3]));
      pv[2*t]   = pk_bf16(fast_tanh(acv[0]), fast_tanh(acv[1]));
      pv[2*t+1] = pk_bf16(fast_tanh(acv[2]), fast_tanh(acv[3]));
    }

    // prefetch next iteration's inputs; HBM latency hides under layers 2-4
    {
      int bn = b + nwaves_total;
      if (bn < nbatch && q == 0) {
        int iu = (bn << 5) + c, iv = iu + 16;
        b1u0 = pk_bf16(Xg[iu], Yg[iu]); b1u1 = pk_bf16(C1g[iu], C2g[iu]);
        b1v0 = pk_bf16(Xg[iv], Yg[iv]); b1v1 = pk_bf16(C1g[iv], C2g[iv]);
      }
    }

    // ---- layers 2 and 3: activations never leave registers ----
    u32 qu[16], qv[16];
    LAYER_FC(pu, pv, qu, qv, LDS_W2, LDS_B2);
    LAYER_FC(qu, qv, pu, pv, LDS_W3, LDS_B3);

    // ---- layer 4 (N... M=2 in padded 16-tile), bias via C-init rows 0/1 ----
    f32x4 acu = {b4_0, b4_1, 0.f, 0.f};
    f32x4 acv = acu;
#pragma unroll
    for (int ks = 0; ks < 4; ks++) {
      bf16x8 aw = *(const bf16x8*)(lds + LDS_W4 + w4addr + ks * 64);
      acu = MFMA16(aw, mk_frag(pu[4*ks], pu[4*ks+1], pu[4*ks+2], pu[4*ks+3]), acu);
      acv = MFMA16(aw, mk_frag(pv[4*ks], pv[4*ks+1], pv[4*ks+2], pv[4*ks+3]), acv);
    }
    if (q == 0) {
      f32x2 ou = {acu[0], acu[1]}, ov = {acv[0], acv[1]};
      *(f32x2*)(Og + (size_t)(pb + c) * 2)      = ou;
      *(f32x2*)(Og + (size_t)(pb + 16 + c) * 2) = ov;
    }
  }
}

extern "C" void kernel_launch(void* const* d_in, const int* in_sizes, int n_in,
                              void* d_out, int out_size, void* d_ws, size_t ws_size,
                              hipStream_t stream)
{
  (void)n_in; (void)out_size; (void)d_ws; (void)ws_size;
  const float* X  = (const float*)d_in[0];
  const float* Y  = (const float*)d_in[1];
  const float* C1 = (const float*)d_in[2];
  const float* C2 = (const float*)d_in[3];
  const float* W1 = (const float*)d_in[4];
  const float* B1 = (const float*)d_in[5];
  const float* W2 = (const float*)d_in[6];
  const float* B2 = (const float*)d_in[7];
  const float* W3 = (const float*)d_in[8];
  const float* B3 = (const float*)d_in[9];
  const float* W4 = (const float*)d_in[10];
  const float* B4 = (const float*)d_in[11];
  int npts = in_sizes[0];
  const int nblk = 512;               // 2 WGs/CU (LDS 69120 B each), 8 waves per WG
  const int nwaves = nblk * 8;
  hipLaunchKernelGGL(mlp_fused, dim3(nblk), dim3(512), LDS_TOTAL, stream,
                     X, Y, C1, C2, W1, B1, W2, B2, W3, B3, W4, B4,
                     (float*)d_out, npts, nwaves);
}

// Round 2
// 289.398 us; speedup vs baseline: 1.3789x; 1.3789x over previous
//
#include <hip/hip_runtime.h>
#include <hip/hip_bf16.h>

using u16 = unsigned short;
using u32 = unsigned int;

typedef __attribute__((ext_vector_type(8))) short bf16x8;
typedef __attribute__((ext_vector_type(4))) float f32x4;
typedef __attribute__((ext_vector_type(2))) float f32x2;
typedef __attribute__((ext_vector_type(4))) u32 u32x4;

#define MFMA16(a, b, c) __builtin_amdgcn_mfma_f32_16x16x32_bf16((a), (b), (c), 0, 0, 0)

union FragU { u32 u[4]; bf16x8 v; u32x4 q; };

__device__ __forceinline__ bf16x8 mk_frag(u32 a, u32 b, u32 c, u32 d) {
  FragU f; f.u[0] = a; f.u[1] = b; f.u[2] = c; f.u[3] = d; return f.v;
}
__device__ __forceinline__ bf16x8 as_frag(u32x4 x) { FragU f; f.q = x; return f.v; }

__device__ __forceinline__ u16 f2bf(float x) {
  __hip_bfloat16 h = __float2bfloat16(x);
  u16 r; __builtin_memcpy(&r, &h, 2); return r;
}

__device__ __forceinline__ u32 pk_bf16(float a, float b) {
  __hip_bfloat162 h = __float22bfloat162_rn(make_float2(a, b));
  u32 r; __builtin_memcpy(&r, &h, 4); return r;
}

__device__ __forceinline__ float fast_tanh(float x) {
  // tanh(x) = 1 - 2/(1 + exp2(x * 2*log2(e)))
  float t = __builtin_amdgcn_exp2f(x * 2.885390081777927f);
  return __builtin_fmaf(-2.0f, __builtin_amdgcn_rcpf(1.0f + t), 1.0f);
}

// Flipped orientation: every layer computes D[hidden][point] with A = W^T, B = activations.
// With contraction order K(ks,8q+j) = 32ks + 16*(j>>2) + 4q + (j&3), the next layer's
// B-fragment is exactly the lane's OWN packed tanh outputs of D-tiles 2ks, 2ks+1:
//   Bfrag(ks) = { P[2ks][0], P[2ks][1], P[2ks+1][0], P[2ks+1][1] },
//   P[t][w] = pk_bf16(tanh(acc_t[2w]), tanh(acc_t[2w+1]))   (rows 16t+4q+{0..3}, col = point c)
// => activations stay in registers; no LDS hbuf, no shuffles, no repacks.
//
// Register budget is the kill-switch (round-1 lesson): __launch_bounds__ 2nd arg behaves as
// blocks/CU on this toolchain ((512,4) measured VGPR_Count=64 => 32 waves/CU target).
// (512,2) => 16 waves/CU => 128-VGPR cap, matching the LDS limit of 2 WGs/CU.
// Layer 4 is fused into layer 3's tile-pair loop so the L3 output never exists as a
// full 32-word array: peak live ~= qu/qv (32) + transients.

#define LDS_W2 0          // 32768 B
#define LDS_W3 32768      // 32768 B
#define LDS_W4 65536      //   512 B (2 rows x 256)
#define LDS_B2 66048      //   512 B f32[128]
#define LDS_B3 66560      //   512 B f32[128]
#define LDS_W1 67072      //  2048 B (128 rows x 16 B, q==0 A-chunk incl. bias at j=4)
#define LDS_TOTAL 69120   // 2 WGs/CU co-resident (138240 <= 163840)

__global__ void __launch_bounds__(512, 2) mlp_fused(
    const float* __restrict__ Xg, const float* __restrict__ Yg,
    const float* __restrict__ C1g, const float* __restrict__ C2g,
    const float* __restrict__ W1g, const float* __restrict__ B1g,
    const float* __restrict__ W2g, const float* __restrict__ B2g,
    const float* __restrict__ W3g, const float* __restrict__ B3g,
    const float* __restrict__ W4g, const float* __restrict__ B4g,
    float* __restrict__ Og, int npts, int nwaves_total)
{
  extern __shared__ char lds[];
  const int tid = threadIdx.x;

  // ---- stage W2^T / W3^T as K-interleaved, bank-swizzled A-fragments ----
  for (int i = tid; i < 16384; i += 512) {
    int k = i >> 7, n = i & 127;                       // W[k][n], k = hid_in, n = hid_out
    int kc = ((k >> 5) << 2) | ((k >> 2) & 3);         // chunk = 4*ks + q
    int j  = (k & 3) | (((k >> 4) & 1) << 2);          // slot within chunk
    int off = n * 256 + ((kc ^ (n & 15)) << 4) + (j << 1);
    *(u16*)(lds + LDS_W2 + off) = f2bf(W2g[i]);
    *(u16*)(lds + LDS_W3 + off) = f2bf(W3g[i]);
  }
  if (tid < 256) {                                     // W4 is [128][2] row-major
    int k = tid >> 1, o = tid & 1;
    int kc = ((k >> 5) << 2) | ((k >> 2) & 3);
    int j  = (k & 3) | (((k >> 4) & 1) << 2);
    *(u16*)(lds + LDS_W4 + o * 256 + (kc << 4) + (j << 1)) = f2bf(W4g[tid]);
  }
  if (tid < 128) {
    ((float*)(lds + LDS_B2))[tid] = B2g[tid];
    ((float*)(lds + LDS_B3))[tid] = B3g[tid];
    // W1 augmented A-chunk (q==0 only): j=0..3 -> W1[0..3][n], j=4 -> b1[n]
    u32* w1r = (u32*)(lds + LDS_W1 + tid * 16);
    w1r[0] = pk_bf16(W1g[tid],       W1g[128 + tid]);
    w1r[1] = pk_bf16(W1g[256 + tid], W1g[384 + tid]);
    w1r[2] = pk_bf16(B1g[tid], 0.f);
    w1r[3] = 0u;
  }
  __syncthreads();

  const int wave = tid >> 6;
  const int lane = tid & 63;
  const int q = lane >> 4;
  const int c = lane & 15;
  const int wgid = blockIdx.x * 8 + wave;

  int posA[4];
#pragma unroll
  for (int ks = 0; ks < 4; ks++) posA[ks] = c * 256 + (((ks * 4 + q) ^ c) << 4);
  const int biasaddr = q * 16;
  const int w4addr = (c & 1) * 256 + q * 16;   // c>=2 lanes duplicate rows -> unused D rows
  const float b4_0 = B4g[0], b4_1 = B4g[1];

  const int nbatch = npts >> 5;   // 32 points (2 tiles of 16) per wave-iteration

  // software-pipelined input fetch: raw floats stay live across layers 2-4 of the
  // PREVIOUS iteration; packed to bf16 only at the top of their own iteration.
  float fxu = 0.f, fyu = 0.f, f1u = 0.f, f2u = 0.f;
  float fxv = 0.f, fyv = 0.f, f1v = 0.f, f2v = 0.f;
  const u32 b1w2 = (q == 0) ? 0x00003f80u : 0u;   // k=4 slot = 1.0 (bias row)
  if (wgid < nbatch && q == 0) {
    int iu = (wgid << 5) + c, iv = iu + 16;
    fxu = Xg[iu]; fyu = Yg[iu]; f1u = C1g[iu]; f2u = C2g[iu];
    fxv = Xg[iv]; fyv = Yg[iv]; f1v = C1g[iv]; f2v = C2g[iv];
  }

  for (int b = wgid; b < nbatch; b += nwaves_total) {
    // ---- layer 1 (K=5 augmented; bias folded into A row 4) ----
    const u32 b1u0 = pk_bf16(fxu, fyu), b1u1 = pk_bf16(f1u, f2u);
    const u32 b1v0 = pk_bf16(fxv, fyv), b1v1 = pk_bf16(f1v, f2v);
    u32 pu[16], pv[16];
#pragma unroll
    for (int t = 0; t < 8; t++) {
      u32x4 wf = {0u, 0u, 0u, 0u};
      if (q == 0) wf = *(const u32x4*)(lds + LDS_W1 + t * 256 + c * 16);
      f32x4 z = {0.f, 0.f, 0.f, 0.f};
      f32x4 acu = MFMA16(as_frag(wf), mk_frag(b1u0, b1u1, b1w2, 0u), z);
      f32x4 acv = MFMA16(as_frag(wf), mk_frag(b1v0, b1v1, b1w2, 0u), z);
      pu[2*t]   = pk_bf16(fast_tanh(acu[0]), fast_tanh(acu[1]));
      pu[2*t+1] = pk_bf16(fast_tanh(acu[2]), fast_tanh(acu[3]));
      pv[2*t]   = pk_bf16(fast_tanh(acv[0]), fast_tanh(acv[1]));
      pv[2*t+1] = pk_bf16(fast_tanh(acv[2]), fast_tanh(acv[3]));
    }

    // prefetch next iteration's inputs; HBM latency hides under layers 2-4
    {
      int bn = b + nwaves_total;
      if (bn < nbatch && q == 0) {
        int iu = (bn << 5) + c, iv = iu + 16;
        fxu = Xg[iu]; fyu = Yg[iu]; f1u = C1g[iu]; f2u = C2g[iu];
        fxv = Xg[iv]; fyv = Yg[iv]; f1v = C1g[iv]; f2v = C2g[iv];
      }
    }

    // ---- layer 2: registers -> registers ----
    u32 qu[16], qv[16];
#pragma unroll
    for (int t = 0; t < 8; t++) {
      f32x4 bi = *(const f32x4*)(lds + LDS_B2 + t * 64 + biasaddr);
      f32x4 acu = bi, acv = bi;
#pragma unroll
      for (int ks = 0; ks < 4; ks++) {
        bf16x8 aw = *(const bf16x8*)(lds + LDS_W2 + t * 4096 + posA[ks]);
        acu = MFMA16(aw, mk_frag(pu[4*ks], pu[4*ks+1], pu[4*ks+2], pu[4*ks+3]), acu);
        acv = MFMA16(aw, mk_frag(pv[4*ks], pv[4*ks+1], pv[4*ks+2], pv[4*ks+3]), acv);
      }
      qu[2*t]   = pk_bf16(fast_tanh(acu[0]), fast_tanh(acu[1]));
      qu[2*t+1] = pk_bf16(fast_tanh(acu[2]), fast_tanh(acu[3]));
      qv[2*t]   = pk_bf16(fast_tanh(acv[0]), fast_tanh(acv[1]));
      qv[2*t+1] = pk_bf16(fast_tanh(acv[2]), fast_tanh(acv[3]));
    }

    // ---- layer 3 fused with layer 4: L3's tile-pair output feeds L4's ks-MFMA
    // immediately, so it never lives as a full 32-word array ----
    f32x4 acu4 = {b4_0, b4_1, 0.f, 0.f};
    f32x4 acv4 = acu4;
#pragma unroll
    for (int tp = 0; tp < 4; tp++) {
      u32 pwu[4], pwv[4];
#pragma unroll
      for (int h = 0; h < 2; h++) {
        int t = tp * 2 + h;
        f32x4 bi = *(const f32x4*)(lds + LDS_B3 + t * 64 + biasaddr);
        f32x4 acu = bi, acv = bi;
#pragma unroll
        for (int ks = 0; ks < 4; ks++) {
          bf16x8 aw = *(const bf16x8*)(lds + LDS_W3 + t * 4096 + posA[ks]);
          acu = MFMA16(aw, mk_frag(qu[4*ks], qu[4*ks+1], qu[4*ks+2], qu[4*ks+3]), acu);
          acv = MFMA16(aw, mk_frag(qv[4*ks], qv[4*ks+1], qv[4*ks+2], qv[4*ks+3]), acv);
        }
        pwu[2*h]   = pk_bf16(fast_tanh(acu[0]), fast_tanh(acu[1]));
        pwu[2*h+1] = pk_bf16(fast_tanh(acu[2]), fast_tanh(acu[3]));
        pwv[2*h]   = pk_bf16(fast_tanh(acv[0]), fast_tanh(acv[1]));
        pwv[2*h+1] = pk_bf16(fast_tanh(acv[2]), fast_tanh(acv[3]));
      }
      bf16x8 aw4 = *(const bf16x8*)(lds + LDS_W4 + w4addr + tp * 64);
      acu4 = MFMA16(aw4, mk_frag(pwu[0], pwu[1], pwu[2], pwu[3]), acu4);
      acv4 = MFMA16(aw4, mk_frag(pwv[0], pwv[1], pwv[2], pwv[3]), acv4);
    }

    // ---- store (rows 0/1 of the padded N=16 tile are the two logits) ----
    if (q == 0) {
      const int pb = b << 5;
      f32x2 ou = {acu4[0], acu4[1]}, ov = {acv4[0], acv4[1]};
      *(f32x2*)(Og + (size_t)(pb + c) * 2)      = ou;
      *(f32x2*)(Og + (size_t)(pb + 16 + c) * 2) = ov;
    }
  }
}

extern "C" void kernel_launch(void* const* d_in, const int* in_sizes, int n_in,
                              void* d_out, int out_size, void* d_ws, size_t ws_size,
                              hipStream_t stream)
{
  (void)n_in; (void)out_size; (void)d_ws; (void)ws_size;
  const float* X  = (const float*)d_in[0];
  const float* Y  = (const float*)d_in[1];
  const float* C1 = (const float*)d_in[2];
  const float* C2 = (const float*)d_in[3];
  const float* W1 = (const float*)d_in[4];
  const float* B1 = (const float*)d_in[5];
  const float* W2 = (const float*)d_in[6];
  const float* B2 = (const float*)d_in[7];
  const float* W3 = (const float*)d_in[8];
  const float* B3 = (const float*)d_in[9];
  const float* W4 = (const float*)d_in[10];
  const float* B4 = (const float*)d_in[11];
  int npts = in_sizes[0];
  const int nblk = 512;               // 2 WGs/CU (LDS 69120 B each), 8 waves per WG
  const int nwaves = nblk * 8;
  hipLaunchKernelGGL(mlp_fused, dim3(nblk), dim3(512), LDS_TOTAL, stream,
                     X, Y, C1, C2, W1, B1, W2, B2, W3, B3, W4, B4,
                     (float*)d_out, npts, nwaves);
}